// Round 8
// baseline (207.893 us; speedup 1.0000x reference)
//
#include <hip/hip_runtime.h>

namespace {

typedef _Float16 half_t;
typedef _Float16 half2_t __attribute__((ext_vector_type(2)));
typedef _Float16 half4_t __attribute__((ext_vector_type(4)));

constexpr int Wd = 160, Hd = 192, Dd = 160;
constexpr int TX = 16, TY = 16, CZ = 20;
constexpr int HW = Hd * Wd;
constexpr int LIVE = CZ + 8;               // 28 slices per block
constexpr float INV_K = 1.0f / 729.0f;
constexpr float INV_TOT = 1.0f / 9830400.0f;   // 2*160*192*160
constexpr int R4 = 17;     // xs4h row stride in half4 units (16 cols + 1 pad)
constexpr int RTH = 68;    // xsTh row stride in half units (x at 4*x)
constexpr int ROWS = 26;   // 24 halo rows + 2 pad rows absorbing lanes 240..255

// ROUND 8: occupancy experiment. Round 7 proved the 64-VGPR choice is not an
// occupancy-chase (exact 4-wave pin didn't move it) and spill is a bounded
// once-per-thread state dump (WRITE constant 284 B/thread). No pipe is
// saturated (VALU 39%, LDS ~40%, HBM 36%) at Occupancy 33% -- the grid
// (960 blocks = 3.75/CU) is the binding constraint. CZ 40->20 doubles the
// grid to 1920 = 7.5 blocks/CU; at 64 VGPR + 14.3 KB LDS, 8 blocks/CU fit.
// Cost: z-halo work & fetch x1.17.

__global__ __launch_bounds__(256, 4)
void ncc_main(const float* __restrict__ inp, const float* __restrict__ tgt,
              float* __restrict__ out)
{
    __shared__ half4_t xs4h[2][ROWS * R4];   // 2 x 3536 B
    __shared__ half_t  xsTh[2][ROWS * RTH];  // 2 x 3536 B
    __shared__ float   red[4];

    const int tid = threadIdx.x;
    const int n  = (int)blockIdx.z >> 3;
    const int zc = (int)blockIdx.z & 7;
    const int x0 = blockIdx.x * TX, y0 = blockIdx.y * TY, z0 = zc * CZ;

    // ---- phase-1 decode: (row r 0..25) x (half h) x (field f)
    const int f = tid % 5;
    const int j = tid / 5;
    const int r = j >> 1, h = j & 1;
    const int gy = y0 - 4 + r;
    const bool yok = (tid < 240) && (gy >= 0) && (gy < Hd);
    const int gyc = min(max(gy, 0), Hd - 1);
    const int gxb = x0 - 4 + 8 * h;
    const bool uI = (f == 0) || (f == 1) || (f == 3);
    const float bI = (f == 0) ? 1.f : 0.f;
    const float bT = (f == 1 || f == 2) ? 0.5f : 0.f;
    const float bC = (f == 1 || f == 2) ? 0.5f : ((f >= 3) ? 1.f : 0.f);

#define DECODE(c) \
    int voff##c; float aI##c, aTC##c; \
    { const int gx = gxb + 4 * c; \
      const float m = (yok && gx >= 0 && gx < Wd) ? 1.f : 0.f; \
      const int gxc = min(max(gx, 0), Wd - 4); \
      voff##c = gyc * Wd + gxc; \
      aI##c = uI ? m : 0.f; aTC##c = uI ? 0.f : 0.5f * m; }
    DECODE(0) DECODE(1) DECODE(2) DECODE(3)
#undef DECODE

    const int nb = n * (Dd * HW);            // < 2^24, int math is exact
    const float* baseI = inp + nb;           // uniform -> SGPR pair
    const float* baseT = tgt + nb;

    // unified store base (both layouts are stride-4 halves): static imm offsets
    const int stoff = (f < 4) ? ((r * R4) * 4 + 32 * h + f) : (r * RTH + 32 * h);
    half_t* const st0 = (f < 4) ? ((half_t*)xs4h[0] + stoff) : (xsTh[0] + stoff);
    half_t* const st1 = (f < 4) ? ((half_t*)xs4h[1] + stoff) : (xsTh[1] + stoff);

    // ---- phase-2 decode: one output column (yi, xi)
    const int yi = tid >> 4, xi = tid & 15;
    const half4_t* const rd4_0 = &xs4h[0][yi * R4 + xi];
    const half4_t* const rd4_1 = &xs4h[1][yi * R4 + xi];
    const half_t*  const rdT_0 = &xsTh[0][yi * RTH + 4 * xi];
    const half_t*  const rdT_1 = &xsTh[1][yi * RTH + 4 * xi];

    // z-ring as NAMED shift-register slots (27 VGPRs). S in f32: add and
    // subtract of the same cvt'd value 9 slices apart -> no drift.
    const half2_t hz = {(half_t)0.f, (half_t)0.f};
    half2_t R01_0=hz,R01_1=hz,R01_2=hz,R01_3=hz,R01_4=hz,R01_5=hz,R01_6=hz,R01_7=hz,R01_8=hz;
    half2_t R23_0=hz,R23_1=hz,R23_2=hz,R23_3=hz,R23_4=hz,R23_5=hz,R23_6=hz,R23_7=hz,R23_8=hz;
    float   RT_0=0.f,RT_1=0.f,RT_2=0.f,RT_3=0.f,RT_4=0.f,RT_5=0.f,RT_6=0.f,RT_7=0.f,RT_8=0.f;
    float4 S4 = make_float4(0.f, 0.f, 0.f, 0.f);
    float ST = 0.f, acc = 0.f;

    float4 Ic0, Ic1, Ic2, Ic3, Tc0, Tc1, Tc2, Tc3;
    Ic0 = Ic1 = Ic2 = Ic3 = make_float4(0.f, 0.f, 0.f, 0.f);
    Tc0 = Tc1 = Tc2 = Tc3 = Ic0;

#define PRELOAD(zz) { \
    const float* pI = baseI + (zz) * HW; \
    const float* pT = baseT + (zz) * HW; \
    Ic0 = *(const float4*)(pI + voff0); Tc0 = *(const float4*)(pT + voff0); \
    Ic1 = *(const float4*)(pI + voff1); Tc1 = *(const float4*)(pT + voff1); \
    Ic2 = *(const float4*)(pI + voff2); Tc2 = *(const float4*)(pT + voff2); \
    Ic3 = *(const float4*)(pI + voff3); Tc3 = *(const float4*)(pT + voff3); }

    // prologue: prefetch slice s=0 (zi=z0-4); invalid only for zc==0
    if (z0 - 4 >= 0) PRELOAD(z0 - 4)

#define PRODC(c, P0, P1, P2, P3) { \
    P0 = fmaf(Ic##c.x, aI##c, fmaf(Tc##c.x, aTC##c, aTC##c)) * fmaf(Ic##c.x, bI, fmaf(Tc##c.x, bT, bC)); \
    P1 = fmaf(Ic##c.y, aI##c, fmaf(Tc##c.y, aTC##c, aTC##c)) * fmaf(Ic##c.y, bI, fmaf(Tc##c.y, bT, bC)); \
    P2 = fmaf(Ic##c.z, aI##c, fmaf(Tc##c.z, aTC##c, aTC##c)) * fmaf(Ic##c.z, bI, fmaf(Tc##c.z, bT, bC)); \
    P3 = fmaf(Ic##c.w, aI##c, fmaf(Tc##c.w, aTC##c, aTC##c)) * fmaf(Ic##c.w, bI, fmaf(Tc##c.w, bT, bC)); }

#define SHIFT9(P, NV) \
    P##_0 = P##_1; P##_1 = P##_2; P##_2 = P##_3; P##_3 = P##_4; P##_4 = P##_5; \
    P##_5 = P##_6; P##_6 = P##_7; P##_7 = P##_8; P##_8 = (NV);

    for (int tb = 0; tb < 36; tb += 18) {          // 28 live; 18-unroll -> static parity
        #pragma unroll
        for (int u = 0; u < 18; ++u) {
            const int s = tb + u;                  // block-uniform
            if (s < LIVE) {
                const int zi = z0 - 4 + s;
                const bool zok = (zi >= 0) && (zi < Dd);    // uniform
                const int pb = u & 1;              // static plane parity

                // ---- phase-1a: products from prefetched regs (named p0..p15)
                float p0, p1, p2, p3, p4, p5, p6, p7, p8, p9, p10, p11, p12, p13, p14, p15;
                if (zok) {
                    PRODC(0, p0,  p1,  p2,  p3)
                    PRODC(1, p4,  p5,  p6,  p7)
                    PRODC(2, p8,  p9,  p10, p11)
                    PRODC(3, p12, p13, p14, p15)
                }

                // ---- prefetch slice s+1 (in flight over stores+barrier+phase-2)
                {
                    const int zi2 = z0 - 3 + s;
                    if ((s + 1) < LIVE && zi2 >= 0 && zi2 < Dd) PRELOAD(zi2)
                }

                // ---- phase-1b: sliding x-window, fp16 stores to plane[pb]
                if (zok) {
                    half_t* const st = pb ? st1 : st0;
                    float ss = p0 + p1 + p2 + p3 + p4 + p5 + p6 + p7 + p8;
                    st[0]  = (half_t)ss;
                    ss += p9  - p0; st[4]  = (half_t)ss;
                    ss += p10 - p1; st[8]  = (half_t)ss;
                    ss += p11 - p2; st[12] = (half_t)ss;
                    ss += p12 - p3; st[16] = (half_t)ss;
                    ss += p13 - p4; st[20] = (half_t)ss;
                    ss += p14 - p5; st[24] = (half_t)ss;
                    ss += p15 - p6; st[28] = (half_t)ss;
                }

                __syncthreads();                   // single barrier per slice

                // ---- phase-2: fp16 y-taps (v_pk_add_f16), f32 z-window, cc
                half2_t a01 = hz, a23 = hz;
                float aTf = 0.f;
                if (zok) {
                    const half4_t* const rd4 = pb ? rd4_1 : rd4_0;
                    const half_t*  const rdT = pb ? rdT_1 : rdT_0;
                    half_t aT = (half_t)0.f;
                    #pragma unroll
                    for (int k = 0; k < 9; ++k) {
                        const half4_t v = rd4[k * R4];
                        const half2_t vlo = {v.x, v.y};
                        const half2_t vhi = {v.z, v.w};
                        a01 += vlo; a23 += vhi;
                        aT += rdT[k * RTH];
                    }
                    aTf = (float)aT;
                }

                // S update + ring shift (unconditional: pad slices insert 0)
                S4.x += (float)a01.x - (float)R01_0.x;
                S4.y += (float)a01.y - (float)R01_0.y;
                S4.z += (float)a23.x - (float)R23_0.x;
                S4.w += (float)a23.y - (float)R23_0.y;
                ST   += aTf - RT_0;
                SHIFT9(R01, a01)
                SHIFT9(R23, a23)
                SHIFT9(RT, aTf)

                if (s >= 8) {                      // output voxel z = z0 + s - 8
                    const float sii = S4.x, sit = S4.y, stt = S4.z, si = S4.w, stv = ST;
                    const float cross = sit - si * stv * INV_K;
                    const float tvar  = stt - stv * stv * INV_K;
                    const float ivar  = sii - si  * si  * INV_K;
                    acc += cross * cross * __builtin_amdgcn_rcpf(tvar * ivar + 1e-5f);
                }
            }
        }
    }
#undef PRELOAD
#undef PRODC
#undef SHIFT9

    // ---- block reduction + fused finalize (one atomic per block)
    #pragma unroll
    for (int off = 32; off > 0; off >>= 1) acc += __shfl_down(acc, off, 64);
    if ((tid & 63) == 0) red[tid >> 6] = acc;
    __syncthreads();
    if (tid == 0) {
        const float tot = red[0] + red[1] + red[2] + red[3];
        atomicAdd(out, -tot * INV_TOT);
    }
}

} // namespace

extern "C" void kernel_launch(void* const* d_in, const int* in_sizes, int n_in,
                              void* d_out, int out_size, void* d_ws, size_t ws_size,
                              hipStream_t stream)
{
    const float* inp = (const float*)d_in[0];
    const float* tgt = (const float*)d_in[1];
    float* out = (float*)d_out;

    hipMemsetAsync(d_out, 0, sizeof(float), stream);   // d_out re-poisoned each call
    dim3 grid(Wd / TX, Hd / TY, 2 * (Dd / CZ));        // (10,12,16) = 1920 blocks
    ncc_main<<<grid, 256, 0, stream>>>(inp, tgt, out);
}

// Round 9
// 170.250 us; speedup vs baseline: 1.2211x; 1.2211x over previous
//
#include <hip/hip_runtime.h>

namespace {

typedef _Float16 half_t;
typedef _Float16 half2_t __attribute__((ext_vector_type(2)));
typedef _Float16 half4_t __attribute__((ext_vector_type(4)));

constexpr int Wd = 160, Hd = 192, Dd = 160;
constexpr int TX = 16, TY = 16, CZ = 40;
constexpr int HW = Hd * Wd;
constexpr int LIVE = CZ + 8;               // 48 slices per block
constexpr float INV_K = 1.0f / 729.0f;
constexpr float INV_TOT = 1.0f / 9830400.0f;   // 2*160*192*160
constexpr int R4 = 17;     // xs4h row stride in half4 units (16 cols + 1 pad)
constexpr int RTH = 68;    // xsTh row stride in half units (x at 4*x)
constexpr int ROWS = 26;   // 24 halo rows + 2 pad rows absorbing lanes 240..255

// ROUND 9: kill the per-slice spill (R8: WRITE ~6 B/thread/slice, fixed
// block-slice throughput regardless of occupancy). The allocator's VGPR
// choice tracks LDS size (R1: 64.5KB->88 regs; R2-8: <=28KB->64 regs): small
// LDS lets it target 8 waves/EU -> 64-reg budget -> spills the 27-reg ring.
// Fix: move the z-ring into LDS per-thread slots (stride-4, conflict-free,
// thread-private -> NO sync) -- frees 27 loop-carried VGPRs AND pushes LDS
// to 41.8 KB -> 3 blocks/CU target -> register budget ~170 -> no spill.
// CZ back to 40 (R8 proved extra blocks don't help; minimize halo work).

__global__ __launch_bounds__(256, 2)
void ncc_main(const float* __restrict__ inp, const float* __restrict__ tgt,
              float* __restrict__ out)
{
    __shared__ half4_t xs4h[2][ROWS * R4];   // 2 x 3536 B
    __shared__ half_t  xsTh[2][ROWS * RTH];  // 2 x 3536 B
    __shared__ half2_t ringA[9 * 256];       // 9216 B: z-ring {II,IT}, per-thread slots
    __shared__ half2_t ringB[9 * 256];       // 9216 B: z-ring {TT,I}
    __shared__ float   ringT[9 * 256];       // 9216 B: z-ring T
    __shared__ float   red[4];

    const int tid = threadIdx.x;
    const int n  = (int)blockIdx.z >> 2;
    const int zc = (int)blockIdx.z & 3;
    const int x0 = blockIdx.x * TX, y0 = blockIdx.y * TY, z0 = zc * CZ;

    // zero the ring (thread-private slots; no sync needed)
    #pragma unroll
    for (int q = 0; q < 9; ++q) {
        ringA[q * 256 + tid] = (half2_t)0;
        ringB[q * 256 + tid] = (half2_t)0;
        ringT[q * 256 + tid] = 0.f;
    }

    // ---- phase-1 decode: (row r 0..25) x (half h) x (field f)
    const int f = tid % 5;
    const int j = tid / 5;
    const int r = j >> 1, h = j & 1;
    const int gy = y0 - 4 + r;
    const bool yok = (tid < 240) && (gy >= 0) && (gy < Hd);
    const int gyc = min(max(gy, 0), Hd - 1);
    const int gxb = x0 - 4 + 8 * h;
    const bool uI = (f == 0) || (f == 1) || (f == 3);
    const float bI = (f == 0) ? 1.f : 0.f;
    const float bT = (f == 1 || f == 2) ? 0.5f : 0.f;
    const float bC = (f == 1 || f == 2) ? 0.5f : ((f >= 3) ? 1.f : 0.f);

#define DECODE(c) \
    int voff##c; float aI##c, aTC##c; \
    { const int gx = gxb + 4 * c; \
      const float m = (yok && gx >= 0 && gx < Wd) ? 1.f : 0.f; \
      const int gxc = min(max(gx, 0), Wd - 4); \
      voff##c = gyc * Wd + gxc; \
      aI##c = uI ? m : 0.f; aTC##c = uI ? 0.f : 0.5f * m; }
    DECODE(0) DECODE(1) DECODE(2) DECODE(3)
#undef DECODE

    const int nb = n * (Dd * HW);            // < 2^24, int math is exact
    const float* baseI = inp + nb;           // uniform -> SGPR pair
    const float* baseT = tgt + nb;

    // unified store base (both layouts are stride-4 halves): static imm offsets
    const int stoff = (f < 4) ? ((r * R4) * 4 + 32 * h + f) : (r * RTH + 32 * h);
    half_t* const st0 = (f < 4) ? ((half_t*)xs4h[0] + stoff) : (xsTh[0] + stoff);
    half_t* const st1 = (f < 4) ? ((half_t*)xs4h[1] + stoff) : (xsTh[1] + stoff);

    // ---- phase-2 decode: one output column (yi, xi)
    const int yi = tid >> 4, xi = tid & 15;
    const half4_t* const rd4_0 = &xs4h[0][yi * R4 + xi];
    const half4_t* const rd4_1 = &xs4h[1][yi * R4 + xi];
    const half_t*  const rdT_0 = &xsTh[0][yi * RTH + 4 * xi];
    const half_t*  const rdT_1 = &xsTh[1][yi * RTH + 4 * xi];

    float4 S4 = make_float4(0.f, 0.f, 0.f, 0.f);
    float ST = 0.f, acc = 0.f;

    float4 Ic0, Ic1, Ic2, Ic3, Tc0, Tc1, Tc2, Tc3;
    Ic0 = Ic1 = Ic2 = Ic3 = make_float4(0.f, 0.f, 0.f, 0.f);
    Tc0 = Tc1 = Tc2 = Tc3 = Ic0;

#define PRELOAD(zz) { \
    const float* pI = baseI + (zz) * HW; \
    const float* pT = baseT + (zz) * HW; \
    Ic0 = *(const float4*)(pI + voff0); Tc0 = *(const float4*)(pT + voff0); \
    Ic1 = *(const float4*)(pI + voff1); Tc1 = *(const float4*)(pT + voff1); \
    Ic2 = *(const float4*)(pI + voff2); Tc2 = *(const float4*)(pT + voff2); \
    Ic3 = *(const float4*)(pI + voff3); Tc3 = *(const float4*)(pT + voff3); }

    // prologue: prefetch slice s=0 (zi=z0-4); invalid only for zc==0
    if (z0 - 4 >= 0) PRELOAD(z0 - 4)

#define PRODC(c, P0, P1, P2, P3) { \
    P0 = fmaf(Ic##c.x, aI##c, fmaf(Tc##c.x, aTC##c, aTC##c)) * fmaf(Ic##c.x, bI, fmaf(Tc##c.x, bT, bC)); \
    P1 = fmaf(Ic##c.y, aI##c, fmaf(Tc##c.y, aTC##c, aTC##c)) * fmaf(Ic##c.y, bI, fmaf(Tc##c.y, bT, bC)); \
    P2 = fmaf(Ic##c.z, aI##c, fmaf(Tc##c.z, aTC##c, aTC##c)) * fmaf(Ic##c.z, bI, fmaf(Tc##c.z, bT, bC)); \
    P3 = fmaf(Ic##c.w, aI##c, fmaf(Tc##c.w, aTC##c, aTC##c)) * fmaf(Ic##c.w, bI, fmaf(Tc##c.w, bT, bC)); }

    for (int tb = 0; tb < 54; tb += 18) {          // 48 live; 18-unroll -> static slot/parity
        #pragma unroll
        for (int u = 0; u < 18; ++u) {
            const int s = tb + u;                  // block-uniform
            if (s < LIVE) {
                const int zi = z0 - 4 + s;
                const bool zok = (zi >= 0) && (zi < Dd);    // uniform
                const int sl = u % 9;              // static (tb % 9 == 0)
                const int pb = u & 1;              // static plane parity

                // ---- phase-1a: products AND full x-window (p's die here,
                // only o0..o7 overlap the in-flight preload)
                float o0, o1, o2, o3, o4, o5, o6, o7;
                if (zok) {
                    float p0, p1, p2, p3, p4, p5, p6, p7;
                    float p8, p9, p10, p11, p12, p13, p14, p15;
                    PRODC(0, p0,  p1,  p2,  p3)
                    PRODC(1, p4,  p5,  p6,  p7)
                    PRODC(2, p8,  p9,  p10, p11)
                    PRODC(3, p12, p13, p14, p15)
                    float ss = p0 + p1 + p2 + p3 + p4 + p5 + p6 + p7 + p8;
                    o0 = ss;
                    ss += p9  - p0; o1 = ss;
                    ss += p10 - p1; o2 = ss;
                    ss += p11 - p2; o3 = ss;
                    ss += p12 - p3; o4 = ss;
                    ss += p13 - p4; o5 = ss;
                    ss += p14 - p5; o6 = ss;
                    ss += p15 - p6; o7 = ss;
                }

                // ---- prefetch slice s+1 (in flight over stores+barrier+phase-2)
                {
                    const int zi2 = z0 - 3 + s;
                    if ((s + 1) < LIVE && zi2 >= 0 && zi2 < Dd) PRELOAD(zi2)
                }

                // ---- phase-1b: fp16 stores to plane[pb] (static imm offsets)
                if (zok) {
                    half_t* const st = pb ? st1 : st0;
                    st[0]  = (half_t)o0; st[4]  = (half_t)o1;
                    st[8]  = (half_t)o2; st[12] = (half_t)o3;
                    st[16] = (half_t)o4; st[20] = (half_t)o5;
                    st[24] = (half_t)o6; st[28] = (half_t)o7;
                }

                __syncthreads();                   // single barrier per slice

                // ---- phase-2: fp16 y-taps (v_pk_add_f16), LDS z-ring, cc
                half2_t a01 = (half2_t)0, a23 = (half2_t)0;
                float aTf = 0.f;
                if (zok) {
                    const half4_t* const rd4 = pb ? rd4_1 : rd4_0;
                    const half_t*  const rdT = pb ? rdT_1 : rdT_0;
                    half_t aT = (half_t)0.f;
                    #pragma unroll
                    for (int k = 0; k < 9; ++k) {
                        const half4_t v = rd4[k * R4];
                        const half2_t vlo = {v.x, v.y};
                        const half2_t vhi = {v.z, v.w};
                        a01 += vlo; a23 += vhi;
                        aT += rdT[k * RTH];
                    }
                    aTf = (float)aT;
                }

                // LDS ring: read old slot, update S, write new (thread-private,
                // conflict-free stride-4, static slot offsets; no sync needed)
                {
                    const half2_t oA = ringA[sl * 256 + tid];
                    const half2_t oB = ringB[sl * 256 + tid];
                    const float   oT = ringT[sl * 256 + tid];
                    S4.x += (float)a01.x - (float)oA.x;
                    S4.y += (float)a01.y - (float)oA.y;
                    S4.z += (float)a23.x - (float)oB.x;
                    S4.w += (float)a23.y - (float)oB.y;
                    ST   += aTf - oT;
                    ringA[sl * 256 + tid] = a01;
                    ringB[sl * 256 + tid] = a23;
                    ringT[sl * 256 + tid] = aTf;
                }

                if (s >= 8) {                      // output voxel z = z0 + s - 8
                    const float sii = S4.x, sit = S4.y, stt = S4.z, si = S4.w, stv = ST;
                    const float cross = sit - si * stv * INV_K;
                    const float tvar  = stt - stv * stv * INV_K;
                    const float ivar  = sii - si  * si  * INV_K;
                    acc += cross * cross * __builtin_amdgcn_rcpf(tvar * ivar + 1e-5f);
                }
            }
        }
    }
#undef PRELOAD
#undef PRODC

    // ---- block reduction + fused finalize (one atomic per block)
    #pragma unroll
    for (int off = 32; off > 0; off >>= 1) acc += __shfl_down(acc, off, 64);
    if ((tid & 63) == 0) red[tid >> 6] = acc;
    __syncthreads();
    if (tid == 0) {
        const float tot = red[0] + red[1] + red[2] + red[3];
        atomicAdd(out, -tot * INV_TOT);
    }
}

} // namespace

extern "C" void kernel_launch(void* const* d_in, const int* in_sizes, int n_in,
                              void* d_out, int out_size, void* d_ws, size_t ws_size,
                              hipStream_t stream)
{
    const float* inp = (const float*)d_in[0];
    const float* tgt = (const float*)d_in[1];
    float* out = (float*)d_out;

    hipMemsetAsync(d_out, 0, sizeof(float), stream);   // d_out re-poisoned each call
    dim3 grid(Wd / TX, Hd / TY, 2 * (Dd / CZ));        // (10,12,8) = 960 blocks
    ncc_main<<<grid, 256, 0, stream>>>(inp, tgt, out);
}

// Round 10
// 166.828 us; speedup vs baseline: 1.2462x; 1.0205x over previous
//
#include <hip/hip_runtime.h>

namespace {

typedef _Float16 half_t;
typedef _Float16 half2_t __attribute__((ext_vector_type(2)));
typedef _Float16 half4_t __attribute__((ext_vector_type(4)));

constexpr int Wd = 160, Hd = 192, Dd = 160;
constexpr int TX = 16, TY = 16, CZ = 40;
constexpr int HW = Hd * Wd;
constexpr int LIVE = CZ + 8;               // 48 slices per block
constexpr float INV_K = 1.0f / 729.0f;
constexpr float INV_TOT = 1.0f / 9830400.0f;   // 2*160*192*160
constexpr int R4 = 17;     // xs4h row stride in half4 units (16 cols + 1 pad)
constexpr int RTH = 68;    // xsTh row stride in half units (x at 4*x)
constexpr int ROWS = 26;   // 24 halo rows + 2 pad rows absorbing lanes 240..255

// ROUND 10: depth-2 register prefetch. R9 arithmetic: 1300 CU-cyc per
// block-slice vs ~690 LDS + ~45% VALU -- no pipe saturated, occupancy
// doesn't help (R8) => per-slice vmcnt stall on the 1-slice-deep preload
// (~500 cyc cover vs ~900 cyc HBM latency, m126). Depth 2 (issue s+2 while
// computing s) covers ~1000+ cyc. Ring shrunk (half4 ringAB + half ringT,
// aT was already f16-summed) -> LDS 37.3 KB -> 4 blocks/CU -> 128-reg
// allocator budget >= ~115 demand. 18-unroll keeps A/B set parity static.

__global__ __launch_bounds__(256, 2)
void ncc_main(const float* __restrict__ inp, const float* __restrict__ tgt,
              float* __restrict__ out)
{
    __shared__ half4_t xs4h[2][ROWS * R4];   // 2 x 3536 B
    __shared__ half_t  xsTh[2][ROWS * RTH];  // 2 x 3536 B
    __shared__ half4_t ringAB[9 * 256];      // 18432 B: z-ring {II,IT,TT,I}
    __shared__ half_t  ringT[9 * 256];       //  4608 B: z-ring {T}
    __shared__ float   red[4];

    const int tid = threadIdx.x;
    const int n  = (int)blockIdx.z >> 2;
    const int zc = (int)blockIdx.z & 3;
    const int x0 = blockIdx.x * TX, y0 = blockIdx.y * TY, z0 = zc * CZ;

    // zero the ring (thread-private slots; no sync needed)
    #pragma unroll
    for (int q = 0; q < 9; ++q) {
        ringAB[q * 256 + tid] = (half4_t)0;
        ringT[q * 256 + tid] = (half_t)0.f;
    }

    // ---- phase-1 decode: (row r 0..25) x (half h) x (field f)
    const int f = tid % 5;
    const int j = tid / 5;
    const int r = j >> 1, h = j & 1;
    const int gy = y0 - 4 + r;
    const bool yok = (tid < 240) && (gy >= 0) && (gy < Hd);
    const int gyc = min(max(gy, 0), Hd - 1);
    const int gxb = x0 - 4 + 8 * h;
    const bool uI = (f == 0) || (f == 1) || (f == 3);
    const float bI = (f == 0) ? 1.f : 0.f;
    const float bT = (f == 1 || f == 2) ? 0.5f : 0.f;
    const float bC = (f == 1 || f == 2) ? 0.5f : ((f >= 3) ? 1.f : 0.f);

#define DECODE(c) \
    int voff##c; float aI##c, aTC##c; \
    { const int gx = gxb + 4 * c; \
      const float m = (yok && gx >= 0 && gx < Wd) ? 1.f : 0.f; \
      const int gxc = min(max(gx, 0), Wd - 4); \
      voff##c = gyc * Wd + gxc; \
      aI##c = uI ? m : 0.f; aTC##c = uI ? 0.f : 0.5f * m; }
    DECODE(0) DECODE(1) DECODE(2) DECODE(3)
#undef DECODE

    const int nb = n * (Dd * HW);            // < 2^24, int math is exact
    const float* baseI = inp + nb;           // uniform -> SGPR pair
    const float* baseT = tgt + nb;

    // unified store base (both layouts are stride-4 halves): static imm offsets
    const int stoff = (f < 4) ? ((r * R4) * 4 + 32 * h + f) : (r * RTH + 32 * h);
    half_t* const st0 = (f < 4) ? ((half_t*)xs4h[0] + stoff) : (xsTh[0] + stoff);
    half_t* const st1 = (f < 4) ? ((half_t*)xs4h[1] + stoff) : (xsTh[1] + stoff);

    // ---- phase-2 decode: one output column (yi, xi)
    const int yi = tid >> 4, xi = tid & 15;
    const half4_t* const rd4_0 = &xs4h[0][yi * R4 + xi];
    const half4_t* const rd4_1 = &xs4h[1][yi * R4 + xi];
    const half_t*  const rdT_0 = &xsTh[0][yi * RTH + 4 * xi];
    const half_t*  const rdT_1 = &xsTh[1][yi * RTH + 4 * xi];

    float4 S4 = make_float4(0.f, 0.f, 0.f, 0.f);
    float ST = 0.f, acc = 0.f;

    // two prefetch sets, roles alternate with static slice parity
#define DECL_SET(S) \
    float4 S##I0, S##I1, S##I2, S##I3, S##T0, S##T1, S##T2, S##T3; \
    S##I0 = S##I1 = S##I2 = S##I3 = make_float4(0.f, 0.f, 0.f, 0.f); \
    S##T0 = S##T1 = S##T2 = S##T3 = S##I0;
    DECL_SET(A) DECL_SET(B)
#undef DECL_SET

#define PRELOAD(S, zz) { \
    const float* pI = baseI + (zz) * HW; \
    const float* pT = baseT + (zz) * HW; \
    S##I0 = *(const float4*)(pI + voff0); S##T0 = *(const float4*)(pT + voff0); \
    S##I1 = *(const float4*)(pI + voff1); S##T1 = *(const float4*)(pT + voff1); \
    S##I2 = *(const float4*)(pI + voff2); S##T2 = *(const float4*)(pT + voff2); \
    S##I3 = *(const float4*)(pI + voff3); S##T3 = *(const float4*)(pT + voff3); }

    // prologue: s=0 -> set A (even), s=1 -> set B (odd)
    if (z0 - 4 >= 0) PRELOAD(A, z0 - 4)
    if (z0 - 3 >= 0) PRELOAD(B, z0 - 3)

#define PRODC(S, c, P0, P1, P2, P3) { \
    P0 = fmaf(S##I##c.x, aI##c, fmaf(S##T##c.x, aTC##c, aTC##c)) * fmaf(S##I##c.x, bI, fmaf(S##T##c.x, bT, bC)); \
    P1 = fmaf(S##I##c.y, aI##c, fmaf(S##T##c.y, aTC##c, aTC##c)) * fmaf(S##I##c.y, bI, fmaf(S##T##c.y, bT, bC)); \
    P2 = fmaf(S##I##c.z, aI##c, fmaf(S##T##c.z, aTC##c, aTC##c)) * fmaf(S##I##c.z, bI, fmaf(S##T##c.z, bT, bC)); \
    P3 = fmaf(S##I##c.w, aI##c, fmaf(S##T##c.w, aTC##c, aTC##c)) * fmaf(S##I##c.w, bI, fmaf(S##T##c.w, bT, bC)); }

    // body for one slice; SET = prefetch set holding slice s, also the
    // target for the s+2 load (same parity)
#define SLICE_BODY(SET) { \
    const int zi = z0 - 4 + s; \
    const bool zok = (zi >= 0) && (zi < Dd);        /* uniform */ \
    const int sl = u % 9;                           /* static */ \
    const int pb = u & 1;                           /* static */ \
    float o0, o1, o2, o3, o4, o5, o6, o7; \
    if (zok) { \
        float p0, p1, p2, p3, p4, p5, p6, p7; \
        float p8, p9, p10, p11, p12, p13, p14, p15; \
        PRODC(SET, 0, p0,  p1,  p2,  p3) \
        PRODC(SET, 1, p4,  p5,  p6,  p7) \
        PRODC(SET, 2, p8,  p9,  p10, p11) \
        PRODC(SET, 3, p12, p13, p14, p15) \
        float ss = p0 + p1 + p2 + p3 + p4 + p5 + p6 + p7 + p8; \
        o0 = ss; \
        ss += p9  - p0; o1 = ss; \
        ss += p10 - p1; o2 = ss; \
        ss += p11 - p2; o3 = ss; \
        ss += p12 - p3; o4 = ss; \
        ss += p13 - p4; o5 = ss; \
        ss += p14 - p5; o6 = ss; \
        ss += p15 - p6; o7 = ss; \
    } \
    {   /* prefetch slice s+2 into the same set (depth-2 pipeline) */ \
        const int zi2 = z0 - 2 + s; \
        if ((s + 2) < LIVE && zi2 >= 0 && zi2 < Dd) PRELOAD(SET, zi2) \
    } \
    if (zok) { \
        half_t* const st = pb ? st1 : st0; \
        st[0]  = (half_t)o0; st[4]  = (half_t)o1; \
        st[8]  = (half_t)o2; st[12] = (half_t)o3; \
        st[16] = (half_t)o4; st[20] = (half_t)o5; \
        st[24] = (half_t)o6; st[28] = (half_t)o7; \
    } \
    __syncthreads();                                /* single barrier */ \
    half2_t a01 = (half2_t)0, a23 = (half2_t)0; \
    half_t aT = (half_t)0.f; \
    if (zok) { \
        const half4_t* const rd4 = pb ? rd4_1 : rd4_0; \
        const half_t*  const rdT = pb ? rdT_1 : rdT_0; \
        _Pragma("unroll") \
        for (int k = 0; k < 9; ++k) { \
            const half4_t v = rd4[k * R4]; \
            const half2_t vlo = {v.x, v.y}; \
            const half2_t vhi = {v.z, v.w}; \
            a01 += vlo; a23 += vhi; \
            aT += rdT[k * RTH]; \
        } \
    } \
    {   /* LDS z-ring (thread-private, static slot offsets, no sync) */ \
        const half4_t oAB = ringAB[sl * 256 + tid]; \
        const half_t  oT  = ringT[sl * 256 + tid]; \
        S4.x += (float)a01.x - (float)oAB.x; \
        S4.y += (float)a01.y - (float)oAB.y; \
        S4.z += (float)a23.x - (float)oAB.z; \
        S4.w += (float)a23.y - (float)oAB.w; \
        ST   += (float)aT - (float)oT; \
        const half4_t nAB = {a01.x, a01.y, a23.x, a23.y}; \
        ringAB[sl * 256 + tid] = nAB; \
        ringT[sl * 256 + tid]  = aT; \
    } \
    if (s >= 8) {                                   /* output z = z0+s-8 */ \
        const float sii = S4.x, sit = S4.y, stt = S4.z, si = S4.w, stv = ST; \
        const float cross = sit - si * stv * INV_K; \
        const float tvar  = stt - stv * stv * INV_K; \
        const float ivar  = sii - si  * si  * INV_K; \
        acc += cross * cross * __builtin_amdgcn_rcpf(tvar * ivar + 1e-5f); \
    } }

    for (int tb = 0; tb < 54; tb += 18) {          // 48 live; 18-unroll
        #pragma unroll
        for (int u = 0; u < 18; ++u) {
            const int s = tb + u;                  // block-uniform
            if (s < LIVE) {
                if ((u & 1) == 0) SLICE_BODY(A)
                else              SLICE_BODY(B)
            }
        }
    }
#undef SLICE_BODY
#undef PRELOAD
#undef PRODC

    // ---- block reduction + fused finalize (one atomic per block)
    #pragma unroll
    for (int off = 32; off > 0; off >>= 1) acc += __shfl_down(acc, off, 64);
    if ((tid & 63) == 0) red[tid >> 6] = acc;
    __syncthreads();
    if (tid == 0) {
        const float tot = red[0] + red[1] + red[2] + red[3];
        atomicAdd(out, -tot * INV_TOT);
    }
}

} // namespace

extern "C" void kernel_launch(void* const* d_in, const int* in_sizes, int n_in,
                              void* d_out, int out_size, void* d_ws, size_t ws_size,
                              hipStream_t stream)
{
    const float* inp = (const float*)d_in[0];
    const float* tgt = (const float*)d_in[1];
    float* out = (float*)d_out;

    hipMemsetAsync(d_out, 0, sizeof(float), stream);   // d_out re-poisoned each call
    dim3 grid(Wd / TX, Hd / TY, 2 * (Dd / CZ));        // (10,12,8) = 960 blocks
    ncc_main<<<grid, 256, 0, stream>>>(inp, tgt, out);
}